// Round 1
// baseline (61.545 us; speedup 1.0000x reference)
//
#include <hip/hip_runtime.h>
#include <math.h>

#define MAXS 256
#define MM 16   // M is 16 in this benchmark (asserted via host sizes)

__device__ __forceinline__ float fexp_(float v, float p) {
    float s = (v > 0.f) ? 1.f : ((v < 0.f) ? -1.f : 0.f);
    return s * powf(fabsf(v) + 1e-6f, p);
}

// ---------------- K0: per-(b,m) prep ----------------
__global__ void k_prep(const float* __restrict__ rot,
                       const float* __restrict__ size,
                       const float* __restrict__ shapep,
                       const float* __restrict__ defo,
                       const float* __restrict__ emb,
                       const float* __restrict__ trans,
                       const int* __restrict__ Sptr,
                       float* __restrict__ Rt,        // [BM][12] : R(9) + t(3)
                       float4* __restrict__ pts,      // [BM][MAXS]
                       float* __restrict__ area_raw,  // [BM]
                       unsigned* __restrict__ d2min,  // [BM][MAXS]
                       int B, int M)
{
    int bm = blockIdx.x;
    int b = bm / M, m = bm % M;
    int S = *Sptr;

    __shared__ int   s_me;
    __shared__ float s_par[7]; // sz0,sz1,sz2,e1,e2,d0,d1

    if (threadIdx.x == 0) {
        // idx_e[b,m] = argmax_i emb[b,i,m] (first max, like jnp.argmax)
        int best_i = 0; float best = emb[(size_t)(b*M + 0)*M + m];
        for (int i = 1; i < M; ++i) {
            float v = emb[(size_t)(b*M + i)*M + m];
            if (v > best) { best = v; best_i = i; }
        }
        s_me = best_i;
        const float* sg = size  + (size_t)(b*M + best_i)*3;
        const float* sh = shapep + (size_t)(b*M + best_i)*2;
        const float* df = defo  + (size_t)(b*M + best_i)*2;
        s_par[0]=sg[0]; s_par[1]=sg[1]; s_par[2]=sg[2];
        s_par[3]=sh[0]; s_par[4]=sh[1];
        s_par[5]=df[0]; s_par[6]=df[1];

        // area from gathered size
        float a0=sg[0], a1=sg[1], a2=sg[2];
        float pa = powf(a0*a1, 1.6f), pb = powf(a0*a2, 1.6f), pc = powf(a1*a2, 1.6f);
        area_raw[bm] = 4.f * 3.14159265358979323846f * powf((pa+pb+pc)*(1.f/3.f), 0.625f);

        // rotation/translation of THIS m (not gathered)
        const float* q = rot + (size_t)(b*M + m)*4;
        float w=q[0], x=q[1], y=q[2], z=q[3];
        float inv = 1.0f / sqrtf(w*w + x*x + y*y + z*z);
        w*=inv; x*=inv; y*=inv; z*=inv;
        float* R = Rt + (size_t)bm*12;
        R[0] = 1.f - 2.f*(y*y + z*z); R[1] = 2.f*(x*y - w*z);       R[2] = 2.f*(x*z + w*y);
        R[3] = 2.f*(x*y + w*z);       R[4] = 1.f - 2.f*(x*x + z*z); R[5] = 2.f*(y*z - w*x);
        R[6] = 2.f*(x*z - w*y);       R[7] = 2.f*(y*z + w*x);       R[8] = 1.f - 2.f*(x*x + y*y);
        const float* tr = trans + (size_t)(b*M + m)*3;
        R[9] = tr[0]; R[10] = tr[1]; R[11] = tr[2];
    }
    __syncthreads();

    float sz0 = s_par[0], sz1 = s_par[1], sz2 = s_par[2];
    float e1  = s_par[3], e2  = s_par[4];
    float df0 = s_par[5], df1 = s_par[6];

    double eta0 = -M_PI*0.5 + 0.05, etaE = M_PI*0.5 - 0.05;
    double om0  = -M_PI + 0.05,     omE  = M_PI - 0.05;
    double deta = (S > 1) ? (etaE - eta0) / (double)(S - 1) : 0.0;
    double dom  = (S > 1) ? (omE  - om0)  / (double)(S - 1) : 0.0;

    for (int s = threadIdx.x; s < S && s < MAXS; s += blockDim.x) {
        float eta   = (float)(eta0 + s * deta);
        float omega = (float)(om0  + s * dom);
        float se, ce, so, co;
        sincosf(eta,   &se, &ce);
        sincosf(omega, &so, &co);
        float fce = fexp_(ce, e1);
        float fse = fexp_(se, e1);
        float fco = fexp_(co, e2);
        float fso = fexp_(so, e2);
        float xx = sz0 * fce * fco;
        float yy = sz1 * fce * fso;
        float zz = sz2 * fse;
        float fx = df0 / sz2 * zz + 1.f;
        float fy = df1 / sz2 * zz + 1.f;
        pts[(size_t)bm*MAXS + s] = make_float4(xx*fx, yy*fy, zz, 0.f);
        d2min[(size_t)bm*MAXS + s] = 0x7f800000u;  // +inf bits
    }
}

// ---------------- K1: distances (d1 per n, d2 per s) ----------------
__global__ void k_dist(const float* __restrict__ pcl,
                       const float* __restrict__ Rt,
                       const float4* __restrict__ pts,
                       const int* __restrict__ Sptr,
                       float* __restrict__ d1,        // [BM][N]
                       unsigned* __restrict__ d2min,  // [BM][MAXS]
                       int B, int M, int N, int nchunk)
{
    int bm    = blockIdx.x / nchunk;
    int chunk = blockIdx.x % nchunk;
    int b = bm / M;
    int S = *Sptr;

    __shared__ float4 lds_pcl[256];
    __shared__ float4 lds_pts[256];
    __shared__ float  s_R[12];

    if (threadIdx.x < 12) s_R[threadIdx.x] = Rt[(size_t)bm*12 + threadIdx.x];
    __syncthreads();

    int n0  = chunk * 256;
    int n   = n0 + threadIdx.x;
    int cnt = min(256, N - n0);

    float qx = 0.f, qy = 0.f, qz = 0.f;
    if (n < N) {
        const float* p = pcl + ((size_t)b*N + n)*3;
        float px = p[0] - s_R[9], py = p[1] - s_R[10], pz = p[2] - s_R[11];
        qx = s_R[0]*px + s_R[1]*py + s_R[2]*pz;
        qy = s_R[3]*px + s_R[4]*py + s_R[5]*pz;
        qz = s_R[6]*px + s_R[7]*py + s_R[8]*pz;
        lds_pcl[threadIdx.x] = make_float4(qx, qy, qz, 0.f);
    }

    float dmin1 = 3.4e38f;
    for (int ts = 0; ts < S && ts < MAXS; ts += 256) {
        int tcnt = min(256, min(S, MAXS) - ts);
        __syncthreads();   // lds_pcl staged / previous tile consumed
        if (threadIdx.x < tcnt) lds_pts[threadIdx.x] = pts[(size_t)bm*MAXS + ts + threadIdx.x];
        __syncthreads();

        // pass A: this thread's n vs all s in tile (broadcast LDS reads)
        if (n < N) {
            for (int s = 0; s < tcnt; ++s) {
                float4 pt = lds_pts[s];
                float dx = pt.x - qx, dy = pt.y - qy, dz = pt.z - qz;
                float d = dx*dx + dy*dy + dz*dz;
                dmin1 = fminf(dmin1, d);
            }
        }
        // pass B: this thread's s vs all n in chunk (broadcast LDS reads)
        if (threadIdx.x < tcnt) {
            float4 pt = lds_pts[threadIdx.x];
            float dmin2 = 3.4e38f;
            for (int j = 0; j < cnt; ++j) {
                float4 qq = lds_pcl[j];
                float dx = pt.x - qq.x, dy = pt.y - qq.y, dz = pt.z - qq.z;
                float d = dx*dx + dy*dy + dz*dz;
                dmin2 = fminf(dmin2, d);
            }
            atomicMin(&d2min[(size_t)bm*MAXS + ts + threadIdx.x], __float_as_uint(dmin2));
        }
    }
    if (n < N) d1[(size_t)bm*N + n] = dmin1;
}

// ---------------- K2: per-point sorted cumprod loss (sort-free) ----------------
__global__ void k_cumsum(const float* __restrict__ d1,   // [BM][N]
                         const float* __restrict__ prob, // [B][M]
                         float* __restrict__ partial1,
                         int B, int N)
{
    int t = blockIdx.x * 256 + threadIdx.x;
    float contrib = 0.f;
    if (t < B*N) {
        int b = t / N, n = t % N;
        float d[MM], p[MM];
        #pragma unroll
        for (int m = 0; m < MM; ++m) {
            d[m] = d1[((size_t)(b*MM + m))*N + n];
            p[m] = prob[b*MM + m];
        }
        #pragma unroll
        for (int m = 0; m < MM; ++m) {
            float prod = 1.f;
            #pragma unroll
            for (int mp = 0; mp < MM; ++mp) {
                bool before = (d[mp] < d[m]) || ((d[mp] == d[m]) && (mp < m));
                prod *= before ? (1.f - p[mp]) : 1.f;
            }
            contrib += d[m] * p[m] * prod;
        }
    }
    __shared__ float red[256];
    red[threadIdx.x] = contrib;
    __syncthreads();
    for (int off = 128; off > 0; off >>= 1) {
        if (threadIdx.x < off) red[threadIdx.x] += red[threadIdx.x + off];
        __syncthreads();
    }
    if (threadIdx.x == 0) partial1[blockIdx.x] = red[0];
}

// ---------------- K3: final combine ----------------
__device__ float block_reduce(float v, float* red) {
    int tid = threadIdx.x;
    red[tid] = v; __syncthreads();
    for (int off = 128; off > 0; off >>= 1) {
        if (tid < off) red[tid] += red[tid + off];
        __syncthreads();
    }
    float r = red[0];
    __syncthreads();
    return r;
}

__global__ void k_final(const float* __restrict__ emb,
                        const float* __restrict__ area_raw,
                        const unsigned* __restrict__ d2min,
                        const float* __restrict__ partial1,
                        const int* __restrict__ Sptr,
                        float* __restrict__ out,
                        int B, int M, int N, int nb1)
{
    int tid = threadIdx.x;
    int S = *Sptr;
    int BM = B * M;
    __shared__ float red[256];
    __shared__ float s_area[256];

    // pcl_to_prim
    float v = 0.f;
    for (int i = tid; i < nb1; i += 256) v += partial1[i];
    float p2p = block_reduce(v, red) / (float)(B * N);

    // stage raw areas
    if (tid < BM) s_area[tid] = area_raw[tid];
    __syncthreads();

    // prim_to_pcl : groups of 4 threads per (b,m)
    float contrib = 0.f;
    int bm = tid >> 2, l = tid & 3;
    if (bm < BM) {
        float s2 = 0.f;
        int Sc = min(S, MAXS);
        for (int s = l; s < Sc; s += 4) {
            float dv = __uint_as_float(d2min[(size_t)bm*MAXS + s]);
            if (dv < 1e30f) s2 += dv;   // (reference maps >=1e30 to 0)
        }
        s2 += __shfl_down(s2, 2, 4);
        s2 += __shfl_down(s2, 1, 4);
        if (l == 0) {
            int bb = bm / M;
            float sumb = 0.f;
            for (int mp = 0; mp < M; ++mp) sumb += s_area[bb*M + mp];
            float w = (float)M * s_area[bm] / sumb;
            contrib = (s2 / (float)S) * w / (float)BM;
        }
    }
    float prim2pcl = block_reduce((l == 0 && bm < BM) ? contrib : 0.f, red);

    // emb_reg
    float a1 = 0.f, a2 = 0.f, a3 = 0.f;
    if (tid < BM) {
        int b = tid / M, m = tid % M;
        float colsum = 0.f, rowsum = 0.f, ew = 0.f;
        for (int i = 0; i < M; ++i) colsum += emb[(size_t)(b*M + i)*M + m];
        for (int j = 0; j < M; ++j) {
            float e = emb[(size_t)(b*M + m)*M + j];
            rowsum += e;
            ew += e * (1.f - e);
        }
        a1 = (colsum - 1.f) * (colsum - 1.f);
        a2 = (rowsum - 1.f) * (rowsum - 1.f);
        a3 = ew;
    }
    float s1 = block_reduce(a1, red);
    float s2r = block_reduce(a2, red);
    float s3 = block_reduce(a3, red);
    float emb_reg = s1 / (float)BM + 10.f * s2r / (float)BM + s3 / (float)(BM * M);

    if (tid == 0) {
        out[1] = p2p;
        out[2] = prim2pcl;
        out[3] = 0.f;
        out[4] = emb_reg;
        out[0] = p2p + prim2pcl + emb_reg;
    }
}

// ---------------- host ----------------
extern "C" void kernel_launch(void* const* d_in, const int* in_sizes, int n_in,
                              void* d_out, int out_size, void* d_ws, size_t ws_size,
                              hipStream_t stream)
{
    const float* pcl    = (const float*)d_in[0];
    const float* trans  = (const float*)d_in[1];
    const float* rot    = (const float*)d_in[2];
    const float* size   = (const float*)d_in[3];
    const float* shapep = (const float*)d_in[4];
    const float* defo   = (const float*)d_in[5];
    const float* prob   = (const float*)d_in[6];
    const float* emb    = (const float*)d_in[7];
    const int*   Sptr   = (const int*)d_in[8];

    int M = in_sizes[7] / in_sizes[6];   // (B*M*M)/(B*M)
    int B = in_sizes[6] / M;
    int N = in_sizes[0] / (3 * B);
    int BM = B * M;

    float* ws = (float*)d_ws;
    size_t off = 0;
    float*    Rt       = ws + off; off += (size_t)BM * 12;
    float4*   pts      = (float4*)(ws + off); off += (size_t)BM * MAXS * 4;
    float*    area_raw = ws + off; off += BM;
    off = (off + 3) & ~(size_t)3;
    float*    d1       = ws + off; off += (size_t)BM * N;
    unsigned* d2min    = (unsigned*)(ws + off); off += (size_t)BM * MAXS;
    float*    partial1 = ws + off;
    int nb1 = (B * N + 255) / 256;
    int nchunk = (N + 255) / 256;

    hipLaunchKernelGGL(k_prep, dim3(BM), dim3(256), 0, stream,
                       rot, size, shapep, defo, emb, trans, Sptr,
                       Rt, pts, area_raw, d2min, B, M);
    hipLaunchKernelGGL(k_dist, dim3(BM * nchunk), dim3(256), 0, stream,
                       pcl, Rt, pts, Sptr, d1, d2min, B, M, N, nchunk);
    hipLaunchKernelGGL(k_cumsum, dim3(nb1), dim3(256), 0, stream,
                       d1, prob, partial1, B, N);
    hipLaunchKernelGGL(k_final, dim3(1), dim3(256), 0, stream,
                       emb, area_raw, d2min, partial1, Sptr, (float*)d_out,
                       B, M, N, nb1);
}

// Round 2
// 61.523 us; speedup vs baseline: 1.0004x; 1.0004x over previous
//
#include <hip/hip_runtime.h>
#include <math.h>

#define MAXS 256
#define MM 16   // M is 16 in this benchmark (asserted via host sizes)

__device__ __forceinline__ float fexp_(float v, float p) {
    float s = (v > 0.f) ? 1.f : ((v < 0.f) ? -1.f : 0.f);
    return s * powf(fabsf(v) + 1e-6f, p);
}

// ---------------- K0: per-(b,m) prep ----------------
__global__ void k_prep(const float* __restrict__ rot,
                       const float* __restrict__ size,
                       const float* __restrict__ shapep,
                       const float* __restrict__ defo,
                       const float* __restrict__ emb,
                       const float* __restrict__ trans,
                       const int* __restrict__ Sptr,
                       float* __restrict__ Rt,        // [BM][12] : R(9) + t(3)
                       float4* __restrict__ pts,      // [BM][MAXS]
                       float* __restrict__ area_raw,  // [BM]
                       unsigned* __restrict__ d2min,  // [BM][MAXS]
                       int B, int M)
{
    int bm = blockIdx.x;
    int b = bm / M, m = bm % M;
    int S = *Sptr;

    __shared__ int   s_me;
    __shared__ float s_par[7]; // sz0,sz1,sz2,e1,e2,d0,d1

    if (threadIdx.x == 0) {
        // idx_e[b,m] = argmax_i emb[b,i,m] (first max, like jnp.argmax)
        int best_i = 0; float best = emb[(size_t)(b*M + 0)*M + m];
        for (int i = 1; i < M; ++i) {
            float v = emb[(size_t)(b*M + i)*M + m];
            if (v > best) { best = v; best_i = i; }
        }
        s_me = best_i;
        const float* sg = size  + (size_t)(b*M + best_i)*3;
        const float* sh = shapep + (size_t)(b*M + best_i)*2;
        const float* df = defo  + (size_t)(b*M + best_i)*2;
        s_par[0]=sg[0]; s_par[1]=sg[1]; s_par[2]=sg[2];
        s_par[3]=sh[0]; s_par[4]=sh[1];
        s_par[5]=df[0]; s_par[6]=df[1];

        // area from gathered size
        float a0=sg[0], a1=sg[1], a2=sg[2];
        float pa = powf(a0*a1, 1.6f), pb = powf(a0*a2, 1.6f), pc = powf(a1*a2, 1.6f);
        area_raw[bm] = 4.f * 3.14159265358979323846f * powf((pa+pb+pc)*(1.f/3.f), 0.625f);

        // rotation/translation of THIS m (not gathered)
        const float* q = rot + (size_t)(b*M + m)*4;
        float w=q[0], x=q[1], y=q[2], z=q[3];
        float inv = 1.0f / sqrtf(w*w + x*x + y*y + z*z);
        w*=inv; x*=inv; y*=inv; z*=inv;
        float* R = Rt + (size_t)bm*12;
        R[0] = 1.f - 2.f*(y*y + z*z); R[1] = 2.f*(x*y - w*z);       R[2] = 2.f*(x*z + w*y);
        R[3] = 2.f*(x*y + w*z);       R[4] = 1.f - 2.f*(x*x + z*z); R[5] = 2.f*(y*z - w*x);
        R[6] = 2.f*(x*z - w*y);       R[7] = 2.f*(y*z + w*x);       R[8] = 1.f - 2.f*(x*x + y*y);
        const float* tr = trans + (size_t)(b*M + m)*3;
        R[9] = tr[0]; R[10] = tr[1]; R[11] = tr[2];
    }
    __syncthreads();

    float sz0 = s_par[0], sz1 = s_par[1], sz2 = s_par[2];
    float e1  = s_par[3], e2  = s_par[4];
    float df0 = s_par[5], df1 = s_par[6];

    double eta0 = -M_PI*0.5 + 0.05, etaE = M_PI*0.5 - 0.05;
    double om0  = -M_PI + 0.05,     omE  = M_PI - 0.05;
    double deta = (S > 1) ? (etaE - eta0) / (double)(S - 1) : 0.0;
    double dom  = (S > 1) ? (omE  - om0)  / (double)(S - 1) : 0.0;

    for (int s = threadIdx.x; s < S && s < MAXS; s += blockDim.x) {
        float eta   = (float)(eta0 + s * deta);
        float omega = (float)(om0  + s * dom);
        float se, ce, so, co;
        sincosf(eta,   &se, &ce);
        sincosf(omega, &so, &co);
        float fce = fexp_(ce, e1);
        float fse = fexp_(se, e1);
        float fco = fexp_(co, e2);
        float fso = fexp_(so, e2);
        float xx = sz0 * fce * fco;
        float yy = sz1 * fce * fso;
        float zz = sz2 * fse;
        float fx = df0 / sz2 * zz + 1.f;
        float fy = df1 / sz2 * zz + 1.f;
        pts[(size_t)bm*MAXS + s] = make_float4(xx*fx, yy*fy, zz, 0.f);
        d2min[(size_t)bm*MAXS + s] = 0x7f800000u;  // +inf bits
    }
}

// ---------------- K1: distances (d1 per n, d2 per s) ----------------
__global__ void k_dist(const float* __restrict__ pcl,
                       const float* __restrict__ Rt,
                       const float4* __restrict__ pts,
                       const int* __restrict__ Sptr,
                       float* __restrict__ d1,        // [BM][N]
                       unsigned* __restrict__ d2min,  // [BM][MAXS]
                       int B, int M, int N, int nchunk)
{
    int bm    = blockIdx.x / nchunk;
    int chunk = blockIdx.x % nchunk;
    int b = bm / M;
    int S = *Sptr;

    __shared__ float4 lds_pcl[256];
    __shared__ float4 lds_pts[256];
    __shared__ float  s_R[12];

    if (threadIdx.x < 12) s_R[threadIdx.x] = Rt[(size_t)bm*12 + threadIdx.x];
    __syncthreads();

    int n0  = chunk * 256;
    int n   = n0 + threadIdx.x;
    int cnt = min(256, N - n0);

    float qx = 0.f, qy = 0.f, qz = 0.f;
    if (n < N) {
        const float* p = pcl + ((size_t)b*N + n)*3;
        float px = p[0] - s_R[9], py = p[1] - s_R[10], pz = p[2] - s_R[11];
        qx = s_R[0]*px + s_R[1]*py + s_R[2]*pz;
        qy = s_R[3]*px + s_R[4]*py + s_R[5]*pz;
        qz = s_R[6]*px + s_R[7]*py + s_R[8]*pz;
        lds_pcl[threadIdx.x] = make_float4(qx, qy, qz, 0.f);
    }

    float dmin1 = 3.4e38f;
    for (int ts = 0; ts < S && ts < MAXS; ts += 256) {
        int tcnt = min(256, min(S, MAXS) - ts);
        __syncthreads();   // lds_pcl staged / previous tile consumed
        if (threadIdx.x < tcnt) lds_pts[threadIdx.x] = pts[(size_t)bm*MAXS + ts + threadIdx.x];
        __syncthreads();

        // pass A: this thread's n vs all s in tile (broadcast LDS reads)
        if (n < N) {
            for (int s = 0; s < tcnt; ++s) {
                float4 pt = lds_pts[s];
                float dx = pt.x - qx, dy = pt.y - qy, dz = pt.z - qz;
                float d = dx*dx + dy*dy + dz*dz;
                dmin1 = fminf(dmin1, d);
            }
        }
        // pass B: this thread's s vs all n in chunk (broadcast LDS reads)
        if (threadIdx.x < tcnt) {
            float4 pt = lds_pts[threadIdx.x];
            float dmin2 = 3.4e38f;
            for (int j = 0; j < cnt; ++j) {
                float4 qq = lds_pcl[j];
                float dx = pt.x - qq.x, dy = pt.y - qq.y, dz = pt.z - qq.z;
                float d = dx*dx + dy*dy + dz*dz;
                dmin2 = fminf(dmin2, d);
            }
            atomicMin(&d2min[(size_t)bm*MAXS + ts + threadIdx.x], __float_as_uint(dmin2));
        }
    }
    if (n < N) d1[(size_t)bm*N + n] = dmin1;
}

// ---------------- K2: per-point sorted cumprod loss (sort-free) ----------------
__global__ void k_cumsum(const float* __restrict__ d1,   // [BM][N]
                         const float* __restrict__ prob, // [B][M]
                         float* __restrict__ partial1,
                         int B, int N)
{
    int t = blockIdx.x * 256 + threadIdx.x;
    float contrib = 0.f;
    if (t < B*N) {
        int b = t / N, n = t % N;
        float d[MM], p[MM];
        #pragma unroll
        for (int m = 0; m < MM; ++m) {
            d[m] = d1[((size_t)(b*MM + m))*N + n];
            p[m] = prob[b*MM + m];
        }
        #pragma unroll
        for (int m = 0; m < MM; ++m) {
            float prod = 1.f;
            #pragma unroll
            for (int mp = 0; mp < MM; ++mp) {
                bool before = (d[mp] < d[m]) || ((d[mp] == d[m]) && (mp < m));
                prod *= before ? (1.f - p[mp]) : 1.f;
            }
            contrib += d[m] * p[m] * prod;
        }
    }
    __shared__ float red[256];
    red[threadIdx.x] = contrib;
    __syncthreads();
    for (int off = 128; off > 0; off >>= 1) {
        if (threadIdx.x < off) red[threadIdx.x] += red[threadIdx.x + off];
        __syncthreads();
    }
    if (threadIdx.x == 0) partial1[blockIdx.x] = red[0];
}

// ---------------- K3: final combine ----------------
__device__ float block_reduce(float v, float* red) {
    int tid = threadIdx.x;
    red[tid] = v; __syncthreads();
    for (int off = 128; off > 0; off >>= 1) {
        if (tid < off) red[tid] += red[tid + off];
        __syncthreads();
    }
    float r = red[0];
    __syncthreads();
    return r;
}

__global__ void k_final(const float* __restrict__ emb,
                        const float* __restrict__ area_raw,
                        const unsigned* __restrict__ d2min,
                        const float* __restrict__ partial1,
                        const int* __restrict__ Sptr,
                        float* __restrict__ out,
                        int B, int M, int N, int nb1)
{
    int tid = threadIdx.x;
    int S = *Sptr;
    int BM = B * M;
    __shared__ float red[256];
    __shared__ float s_area[256];

    // pcl_to_prim
    float v = 0.f;
    for (int i = tid; i < nb1; i += 256) v += partial1[i];
    float p2p = block_reduce(v, red) / (float)(B * N);

    // stage raw areas
    if (tid < BM) s_area[tid] = area_raw[tid];
    __syncthreads();

    // prim_to_pcl : groups of 4 threads per (b,m)
    float contrib = 0.f;
    int bm = tid >> 2, l = tid & 3;
    if (bm < BM) {
        float s2 = 0.f;
        int Sc = min(S, MAXS);
        for (int s = l; s < Sc; s += 4) {
            float dv = __uint_as_float(d2min[(size_t)bm*MAXS + s]);
            if (dv < 1e30f) s2 += dv;   // (reference maps >=1e30 to 0)
        }
        s2 += __shfl_down(s2, 2, 4);
        s2 += __shfl_down(s2, 1, 4);
        if (l == 0) {
            int bb = bm / M;
            float sumb = 0.f;
            for (int mp = 0; mp < M; ++mp) sumb += s_area[bb*M + mp];
            float w = (float)M * s_area[bm] / sumb;
            contrib = (s2 / (float)S) * w / (float)BM;
        }
    }
    float prim2pcl = block_reduce((l == 0 && bm < BM) ? contrib : 0.f, red);

    // emb_reg
    float a1 = 0.f, a2 = 0.f, a3 = 0.f;
    if (tid < BM) {
        int b = tid / M, m = tid % M;
        float colsum = 0.f, rowsum = 0.f, ew = 0.f;
        for (int i = 0; i < M; ++i) colsum += emb[(size_t)(b*M + i)*M + m];
        for (int j = 0; j < M; ++j) {
            float e = emb[(size_t)(b*M + m)*M + j];
            rowsum += e;
            ew += e * (1.f - e);
        }
        a1 = (colsum - 1.f) * (colsum - 1.f);
        a2 = (rowsum - 1.f) * (rowsum - 1.f);
        a3 = ew;
    }
    float s1 = block_reduce(a1, red);
    float s2r = block_reduce(a2, red);
    float s3 = block_reduce(a3, red);
    float emb_reg = s1 / (float)BM + 10.f * s2r / (float)BM + s3 / (float)(BM * M);

    if (tid == 0) {
        out[1] = p2p;
        out[2] = prim2pcl;
        out[3] = 0.f;
        out[4] = emb_reg;
        out[0] = p2p + prim2pcl + emb_reg;
    }
}

// ---------------- host ----------------
extern "C" void kernel_launch(void* const* d_in, const int* in_sizes, int n_in,
                              void* d_out, int out_size, void* d_ws, size_t ws_size,
                              hipStream_t stream)
{
    const float* pcl    = (const float*)d_in[0];
    const float* trans  = (const float*)d_in[1];
    const float* rot    = (const float*)d_in[2];
    const float* size   = (const float*)d_in[3];
    const float* shapep = (const float*)d_in[4];
    const float* defo   = (const float*)d_in[5];
    const float* prob   = (const float*)d_in[6];
    const float* emb    = (const float*)d_in[7];
    const int*   Sptr   = (const int*)d_in[8];

    int M = in_sizes[7] / in_sizes[6];   // (B*M*M)/(B*M)
    int B = in_sizes[6] / M;
    int N = in_sizes[0] / (3 * B);
    int BM = B * M;

    float* ws = (float*)d_ws;
    size_t off = 0;
    float*    Rt       = ws + off; off += (size_t)BM * 12;
    float4*   pts      = (float4*)(ws + off); off += (size_t)BM * MAXS * 4;
    float*    area_raw = ws + off; off += BM;
    off = (off + 3) & ~(size_t)3;
    float*    d1       = ws + off; off += (size_t)BM * N;
    unsigned* d2min    = (unsigned*)(ws + off); off += (size_t)BM * MAXS;
    float*    partial1 = ws + off;
    int nb1 = (B * N + 255) / 256;
    int nchunk = (N + 255) / 256;

    hipLaunchKernelGGL(k_prep, dim3(BM), dim3(256), 0, stream,
                       rot, size, shapep, defo, emb, trans, Sptr,
                       Rt, pts, area_raw, d2min, B, M);
    hipLaunchKernelGGL(k_dist, dim3(BM * nchunk), dim3(256), 0, stream,
                       pcl, Rt, pts, Sptr, d1, d2min, B, M, N, nchunk);
    hipLaunchKernelGGL(k_cumsum, dim3(nb1), dim3(256), 0, stream,
                       d1, prob, partial1, B, N);
    hipLaunchKernelGGL(k_final, dim3(1), dim3(256), 0, stream,
                       emb, area_raw, d2min, partial1, Sptr, (float*)d_out,
                       B, M, N, nb1);
}

// Round 3
// 55.695 us; speedup vs baseline: 1.1050x; 1.1046x over previous
//
#include <hip/hip_runtime.h>
#include <math.h>

#define MAXS 256
#define MM 16   // M is 16 in this benchmark (derived from host sizes)

#define INV_2PI 0.15915494309189535f

__device__ __forceinline__ float fpow_(float x, float p) {
    // x > 0 guaranteed. v_log_f32 = log2, v_exp_f32 = exp2.
    return __builtin_amdgcn_exp2f(p * __builtin_amdgcn_logf(x));
}
__device__ __forceinline__ float fexp_(float v, float p) {
    float s = (v > 0.f) ? 1.f : ((v < 0.f) ? -1.f : 0.f);
    return s * fpow_(fabsf(v) + 1e-6f, p);
}

// ---------------- K0: per-(b,m) prep ----------------
// Writes ptsw[bm][s] = (-2x, -2y, -2z, x^2+y^2+z^2) of the deformed SQ point.
__global__ void k_prep(const float* __restrict__ rot,
                       const float* __restrict__ size,
                       const float* __restrict__ shapep,
                       const float* __restrict__ defo,
                       const float* __restrict__ emb,
                       const float* __restrict__ trans,
                       const int* __restrict__ Sptr,
                       float* __restrict__ Rt,        // [BM][12]
                       float4* __restrict__ ptsw,     // [BM][MAXS]
                       float* __restrict__ area_raw,  // [BM]
                       unsigned* __restrict__ d2min,  // [BM][MAXS]
                       unsigned* __restrict__ counter,
                       int B, int M)
{
    int bm = blockIdx.x;
    int b = bm / M, m = bm % M;
    int S = *Sptr;

    if (bm == 0 && threadIdx.x == 0) *counter = 0u;

    __shared__ float s_par[7]; // sz0,sz1,sz2,e1,e2,d0,d1

    if (threadIdx.x == 0) {
        // idx_e[b,m] = argmax_i emb[b,i,m] (first max)
        int best_i = 0; float best = emb[(size_t)(b*M + 0)*M + m];
        for (int i = 1; i < M; ++i) {
            float v = emb[(size_t)(b*M + i)*M + m];
            if (v > best) { best = v; best_i = i; }
        }
        const float* sg = size   + (size_t)(b*M + best_i)*3;
        const float* sh = shapep + (size_t)(b*M + best_i)*2;
        const float* df = defo   + (size_t)(b*M + best_i)*2;
        s_par[0]=sg[0]; s_par[1]=sg[1]; s_par[2]=sg[2];
        s_par[3]=sh[0]; s_par[4]=sh[1];
        s_par[5]=df[0]; s_par[6]=df[1];

        float a0=sg[0], a1=sg[1], a2=sg[2];
        float pa = fpow_(a0*a1, 1.6f), pb = fpow_(a0*a2, 1.6f), pc = fpow_(a1*a2, 1.6f);
        area_raw[bm] = 4.f * 3.14159265358979323846f * fpow_((pa+pb+pc)*(1.f/3.f), 0.625f);

        const float* q = rot + (size_t)(b*M + m)*4;
        float w=q[0], x=q[1], y=q[2], z=q[3];
        float inv = 1.0f / sqrtf(w*w + x*x + y*y + z*z);
        w*=inv; x*=inv; y*=inv; z*=inv;
        float* R = Rt + (size_t)bm*12;
        R[0] = 1.f - 2.f*(y*y + z*z); R[1] = 2.f*(x*y - w*z);       R[2] = 2.f*(x*z + w*y);
        R[3] = 2.f*(x*y + w*z);       R[4] = 1.f - 2.f*(x*x + z*z); R[5] = 2.f*(y*z - w*x);
        R[6] = 2.f*(x*z - w*y);       R[7] = 2.f*(y*z + w*x);       R[8] = 1.f - 2.f*(x*x + y*y);
        const float* tr = trans + (size_t)(b*M + m)*3;
        R[9] = tr[0]; R[10] = tr[1]; R[11] = tr[2];
    }
    __syncthreads();

    float sz0 = s_par[0], sz1 = s_par[1], sz2 = s_par[2];
    float e1  = s_par[3], e2  = s_par[4];
    float df0 = s_par[5], df1 = s_par[6];

    double eta0 = -M_PI*0.5 + 0.05, etaE = M_PI*0.5 - 0.05;
    double om0  = -M_PI + 0.05,     omE  = M_PI - 0.05;
    double deta = (S > 1) ? (etaE - eta0) / (double)(S - 1) : 0.0;
    double dom  = (S > 1) ? (omE  - om0)  / (double)(S - 1) : 0.0;

    for (int s = threadIdx.x; s < S && s < MAXS; s += blockDim.x) {
        float eta   = (float)(eta0 + s * deta);
        float omega = (float)(om0  + s * dom);
        float se = __builtin_amdgcn_sinf(eta   * INV_2PI);
        float ce = __builtin_amdgcn_cosf(eta   * INV_2PI);
        float so = __builtin_amdgcn_sinf(omega * INV_2PI);
        float co = __builtin_amdgcn_cosf(omega * INV_2PI);
        float fce = fexp_(ce, e1);
        float fse = fexp_(se, e1);
        float fco = fexp_(co, e2);
        float fso = fexp_(so, e2);
        float xx = sz0 * fce * fco;
        float yy = sz1 * fce * fso;
        float zz = sz2 * fse;
        float fx = df0 / sz2 * zz + 1.f;
        float fy = df1 / sz2 * zz + 1.f;
        float px = xx*fx, py = yy*fy, pz = zz;
        ptsw[(size_t)bm*MAXS + s] =
            make_float4(-2.f*px, -2.f*py, -2.f*pz, px*px + py*py + pz*pz);
        d2min[(size_t)bm*MAXS + s] = 0x7f800000u;  // +inf bits
    }
}

// ---------------- K1: distances ----------------
__global__ void k_dist(const float* __restrict__ pcl,
                       const float* __restrict__ Rt,
                       const float4* __restrict__ ptsw,
                       const int* __restrict__ Sptr,
                       float* __restrict__ d1,        // [BM][N]
                       unsigned* __restrict__ d2min,  // [BM][MAXS]
                       int B, int M, int N, int nchunk)
{
    int bm    = blockIdx.x / nchunk;
    int chunk = blockIdx.x - bm*nchunk;
    int b = bm / M;
    int S = min(*Sptr, MAXS);

    // uniform address -> scalar loads
    const float* R = Rt + (size_t)bm*12;
    float R0=R[0],R1=R[1],R2=R[2],R3=R[3],R4=R[4],R5=R[5],
          R6=R[6],R7=R[7],R8=R[8],T0=R[9],T1=R[10],T2=R[11];

    __shared__ float4 lds_pcl[256];

    int n0  = chunk * 256;
    int n   = n0 + (int)threadIdx.x;
    int cnt = min(256, N - n0);

    float qx=0.f, qy=0.f, qz=0.f, h=3.4e38f;
    if (n < N) {
        const float* p = pcl + ((size_t)b*N + n)*3;
        float px = p[0] - T0, py = p[1] - T1, pz = p[2] - T2;
        qx = R0*px + R1*py + R2*pz;
        qy = R3*px + R4*py + R5*pz;
        qz = R6*px + R7*py + R8*pz;
        h  = fmaf(qx,qx, fmaf(qy,qy, qz*qz));
    }
    lds_pcl[threadIdx.x] = make_float4(qx, qy, qz, h);
    __syncthreads();

    const float4* pw = ptsw + (size_t)bm*MAXS;

    // ---- pass A: min over s for this thread's n (pw[s] uniform -> s_load) ----
    {
        float ma=3.4e38f, mb=3.4e38f, mc=3.4e38f, md=3.4e38f;
        int s = 0;
        for (; s + 3 < S; s += 4) {
            float4 w0 = pw[s+0], w1 = pw[s+1], w2 = pw[s+2], w3 = pw[s+3];
            float t0 = fmaf(w0.x,qx, fmaf(w0.y,qy, fmaf(w0.z,qz, w0.w)));
            float t1 = fmaf(w1.x,qx, fmaf(w1.y,qy, fmaf(w1.z,qz, w1.w)));
            float t2 = fmaf(w2.x,qx, fmaf(w2.y,qy, fmaf(w2.z,qz, w2.w)));
            float t3 = fmaf(w3.x,qx, fmaf(w3.y,qy, fmaf(w3.z,qz, w3.w)));
            ma = fminf(ma, t0); mb = fminf(mb, t1);
            mc = fminf(mc, t2); md = fminf(md, t3);
        }
        for (; s < S; ++s) {
            float4 w0 = pw[s];
            ma = fminf(ma, fmaf(w0.x,qx, fmaf(w0.y,qy, fmaf(w0.z,qz, w0.w))));
        }
        float m1 = fminf(fminf(ma, mb), fminf(mc, md));
        if (n < N) d1[(size_t)bm*N + n] = m1 + h;
    }

    // ---- pass B: min over this chunk's n for thread's s ----
    if ((int)threadIdx.x < S) {
        float4 w = pw[threadIdx.x];
        float ma=3.4e38f, mb=3.4e38f, mc=3.4e38f, md=3.4e38f;
        int j = 0;
        for (; j + 3 < cnt; j += 4) {
            float4 a = lds_pcl[j+0], bq = lds_pcl[j+1], c = lds_pcl[j+2], dq = lds_pcl[j+3];
            float t0 = fmaf(w.x,a.x,  fmaf(w.y,a.y,  fmaf(w.z,a.z,  a.w)));
            float t1 = fmaf(w.x,bq.x, fmaf(w.y,bq.y, fmaf(w.z,bq.z, bq.w)));
            float t2 = fmaf(w.x,c.x,  fmaf(w.y,c.y,  fmaf(w.z,c.z,  c.w)));
            float t3 = fmaf(w.x,dq.x, fmaf(w.y,dq.y, fmaf(w.z,dq.z, dq.w)));
            ma = fminf(ma, t0); mb = fminf(mb, t1);
            mc = fminf(mc, t2); md = fminf(md, t3);
        }
        for (; j < cnt; ++j) {
            float4 a = lds_pcl[j];
            ma = fminf(ma, fmaf(w.x,a.x, fmaf(w.y,a.y, fmaf(w.z,a.z, a.w))));
        }
        float m2 = fminf(fminf(ma, mb), fminf(mc, md));
        atomicMin(&d2min[(size_t)bm*MAXS + threadIdx.x], __float_as_uint(m2 + w.w));
    }
}

// ---------------- K2: cumsum partials + (last block) final combine ----------------
__device__ __forceinline__ float block_reduce(float v, float* red) {
    int tid = threadIdx.x;
    red[tid] = v; __syncthreads();
    for (int off = 128; off > 0; off >>= 1) {
        if (tid < off) red[tid] += red[tid + off];
        __syncthreads();
    }
    float r = red[0];
    __syncthreads();
    return r;
}

__global__ void k_tail(const float* __restrict__ d1,   // [BM][N]
                       const float* __restrict__ prob, // [B][M]
                       const float* __restrict__ emb,
                       const float* __restrict__ area_raw,
                       const unsigned* __restrict__ d2min,
                       float* __restrict__ partial1,
                       unsigned* __restrict__ counter,
                       const int* __restrict__ Sptr,
                       float* __restrict__ out,
                       int B, int M, int N, int nb1)
{
    int tid = threadIdx.x;
    int t = blockIdx.x * 256 + tid;
    __shared__ float red[256];

    // ---- phase 1: pcl_to_prim partial ----
    float contrib = 0.f;
    if (t < B*N && M == MM) {
        int b = t / N, n = t - b*N;
        float d[MM], p[MM];
        #pragma unroll
        for (int m = 0; m < MM; ++m) {
            d[m] = d1[((size_t)(b*MM + m))*N + n];
            p[m] = prob[b*MM + m];
        }
        #pragma unroll
        for (int m = 0; m < MM; ++m) {
            float prod = p[m];
            #pragma unroll
            for (int mp = 0; mp < MM; ++mp) {
                if (mp == m) continue;
                bool before = (mp < m) ? (d[mp] <= d[m]) : (d[mp] < d[m]);
                prod *= before ? (1.f - p[mp]) : 1.f;
            }
            contrib += d[m] * prod;
        }
    }
    float psum = block_reduce(contrib, red);
    if (tid == 0) partial1[blockIdx.x] = psum;

    // ---- last-block election ----
    __threadfence();
    __shared__ int s_last;
    if (tid == 0) s_last = (atomicAdd(counter, 1u) == (unsigned)(nb1 - 1)) ? 1 : 0;
    __syncthreads();
    if (!s_last) return;
    __threadfence();  // acquire: see other blocks' partial1

    // ---- final combine (single block) ----
    int S = min(*Sptr, MAXS);
    int BM = B * M;
    __shared__ float s_area[256];

    float v = 0.f;
    for (int i = tid; i < nb1; i += 256) v += partial1[i];
    float p2p = block_reduce(v, red) / (float)(B * N);

    if (tid < BM) s_area[tid] = area_raw[tid];
    __syncthreads();

    float contrib2 = 0.f;
    int bm = tid >> 2, l = tid & 3;
    if (bm < BM) {
        float s2 = 0.f;
        for (int s = l; s < S; s += 4) {
            float dv = __uint_as_float(d2min[(size_t)bm*MAXS + s]);
            if (dv < 1e30f) s2 += dv;
        }
        s2 += __shfl_down(s2, 2, 4);
        s2 += __shfl_down(s2, 1, 4);
        if (l == 0) {
            int bb = bm / M;
            float sumb = 0.f;
            for (int mp = 0; mp < M; ++mp) sumb += s_area[bb*M + mp];
            float w = (float)M * s_area[bm] / sumb;
            contrib2 = (s2 / (float)S) * w / (float)BM;
        }
    }
    float prim2pcl = block_reduce((l == 0 && bm < BM) ? contrib2 : 0.f, red);

    float a1 = 0.f, a2 = 0.f, a3 = 0.f;
    if (tid < BM) {
        int b = tid / M, m = tid - (tid/M)*M;
        float colsum = 0.f, rowsum = 0.f, ew = 0.f;
        for (int i = 0; i < M; ++i) colsum += emb[(size_t)(b*M + i)*M + m];
        for (int j = 0; j < M; ++j) {
            float e = emb[(size_t)(b*M + m)*M + j];
            rowsum += e;
            ew += e * (1.f - e);
        }
        a1 = (colsum - 1.f) * (colsum - 1.f);
        a2 = (rowsum - 1.f) * (rowsum - 1.f);
        a3 = ew;
    }
    float s1  = block_reduce(a1, red);
    float s2r = block_reduce(a2, red);
    float s3  = block_reduce(a3, red);
    float emb_reg = s1 / (float)BM + 10.f * s2r / (float)BM + s3 / (float)(BM * M);

    if (tid == 0) {
        out[1] = p2p;
        out[2] = prim2pcl;
        out[3] = 0.f;
        out[4] = emb_reg;
        out[0] = p2p + prim2pcl + emb_reg;
        *counter = 0u;   // leave no state behind
    }
}

// ---------------- host ----------------
extern "C" void kernel_launch(void* const* d_in, const int* in_sizes, int n_in,
                              void* d_out, int out_size, void* d_ws, size_t ws_size,
                              hipStream_t stream)
{
    const float* pcl    = (const float*)d_in[0];
    const float* trans  = (const float*)d_in[1];
    const float* rot    = (const float*)d_in[2];
    const float* size   = (const float*)d_in[3];
    const float* shapep = (const float*)d_in[4];
    const float* defo   = (const float*)d_in[5];
    const float* prob   = (const float*)d_in[6];
    const float* emb    = (const float*)d_in[7];
    const int*   Sptr   = (const int*)d_in[8];

    int M = in_sizes[7] / in_sizes[6];   // (B*M*M)/(B*M)
    int B = in_sizes[6] / M;
    int N = in_sizes[0] / (3 * B);
    int BM = B * M;

    float* ws = (float*)d_ws;
    size_t off = 0;
    float*    Rt       = ws + off; off += (size_t)BM * 12;     // 16B-aligned after (768 floats)
    float4*   ptsw     = (float4*)(ws + off); off += (size_t)BM * MAXS * 4;
    float*    area_raw = ws + off; off += BM;
    off = (off + 3) & ~(size_t)3;
    float*    d1       = ws + off; off += (size_t)BM * N;
    unsigned* d2min    = (unsigned*)(ws + off); off += (size_t)BM * MAXS;
    float*    partial1 = ws + off; off += 256;
    unsigned* counter  = (unsigned*)(ws + off);

    int nb1    = (B * N + 255) / 256;
    int nchunk = (N + 255) / 256;

    hipLaunchKernelGGL(k_prep, dim3(BM), dim3(256), 0, stream,
                       rot, size, shapep, defo, emb, trans, Sptr,
                       Rt, ptsw, area_raw, d2min, counter, B, M);
    hipLaunchKernelGGL(k_dist, dim3(BM * nchunk), dim3(256), 0, stream,
                       pcl, Rt, ptsw, Sptr, d1, d2min, B, M, N, nchunk);
    hipLaunchKernelGGL(k_tail, dim3(nb1), dim3(256), 0, stream,
                       d1, prob, emb, area_raw, d2min, partial1, counter, Sptr,
                       (float*)d_out, B, M, N, nb1);
}

// Round 4
// 43.536 us; speedup vs baseline: 1.4137x; 1.2793x over previous
//
#include <hip/hip_runtime.h>
#include <math.h>

#define MAXS 256
#define MM 16   // M is 16 in this benchmark (derived from host sizes)

#define INV_2PI 0.15915494309189535f

__device__ __forceinline__ float fpow_(float x, float p) {
    // x > 0 guaranteed. exp2/log2 hardware transcendentals.
    return __builtin_amdgcn_exp2f(p * __builtin_amdgcn_logf(x));
}
__device__ __forceinline__ float fexp_(float v, float p) {
    float s = (v > 0.f) ? 1.f : ((v < 0.f) ? -1.f : 0.f);
    return s * fpow_(fabsf(v) + 1e-6f, p);
}

// ---------------- K0: fused prep + distances ----------------
// grid = BM * nchunk blocks of 256. Each block recomputes its bm's prep
// (redundant across chunks, but parallel and cheap), stages points + its
// pcl chunk in LDS, then:
//   pass A: d1[bm][n]        = min_s ||pt_s - q_n||^2   (per-thread n)
//   pass B: d2part[bm][c][s] = min_{n in chunk} ||.||^2 (per-thread s, no atomics)
__global__ void k_main(const float* __restrict__ pcl,
                       const float* __restrict__ trans,
                       const float* __restrict__ rot,
                       const float* __restrict__ size,
                       const float* __restrict__ shapep,
                       const float* __restrict__ defo,
                       const float* __restrict__ emb,
                       const int* __restrict__ Sptr,
                       float* __restrict__ d1,       // [BM][N]
                       float* __restrict__ d2part,   // [BM][nchunk][256]
                       unsigned* __restrict__ counter,
                       int B, int M, int N, int nchunk)
{
    int bm    = blockIdx.x / nchunk;
    int chunk = blockIdx.x - bm*nchunk;
    int b = bm / M, m = bm - b*M;
    int S = min(*Sptr, MAXS);
    int tid = (int)threadIdx.x;

    if (blockIdx.x == 0 && tid == 0) *counter = 0u;  // k_tail runs after us

    __shared__ float4 lds_pts[MAXS];
    __shared__ float4 lds_pcl[256];
    __shared__ float  s_R[12];
    __shared__ float  s_par[7]; // sz0,sz1,sz2,e1,e2,d0,d1

    // ---- prep: argmax_i emb[b,i,m] via 16-lane shuffle reduce (wave 0) ----
    if (tid < 64) {
        float v = (tid < 16 && tid < M) ? emb[(size_t)(b*M + tid)*M + m] : -3.4e38f;
        int idx = tid;
        #pragma unroll
        for (int off = 1; off < 16; off <<= 1) {
            float ov = __shfl_xor(v, off, 64);
            int   oi = __shfl_xor(idx, off, 64);
            if (ov > v || (ov == v && oi < idx)) { v = ov; idx = oi; }
        }
        if (tid == 0) {
            const float* sg = size   + (size_t)(b*M + idx)*3;
            const float* sh = shapep + (size_t)(b*M + idx)*2;
            const float* df = defo   + (size_t)(b*M + idx)*2;
            s_par[0]=sg[0]; s_par[1]=sg[1]; s_par[2]=sg[2];
            s_par[3]=sh[0]; s_par[4]=sh[1];
            s_par[5]=df[0]; s_par[6]=df[1];

            const float* q = rot + (size_t)(b*M + m)*4;
            float w=q[0], x=q[1], y=q[2], z=q[3];
            float inv = 1.0f / sqrtf(w*w + x*x + y*y + z*z);
            w*=inv; x*=inv; y*=inv; z*=inv;
            s_R[0] = 1.f - 2.f*(y*y + z*z); s_R[1] = 2.f*(x*y - w*z);       s_R[2] = 2.f*(x*z + w*y);
            s_R[3] = 2.f*(x*y + w*z);       s_R[4] = 1.f - 2.f*(x*x + z*z); s_R[5] = 2.f*(y*z - w*x);
            s_R[6] = 2.f*(x*z - w*y);       s_R[7] = 2.f*(y*z + w*x);       s_R[8] = 1.f - 2.f*(x*x + y*y);
            const float* tr = trans + (size_t)(b*M + m)*3;
            s_R[9] = tr[0]; s_R[10] = tr[1]; s_R[11] = tr[2];
        }
    }
    __syncthreads();

    // ---- prep: superquadric points -> LDS as (-2x,-2y,-2z, |p|^2) ----
    {
        float sz0 = s_par[0], sz1 = s_par[1], sz2 = s_par[2];
        float e1  = s_par[3], e2  = s_par[4];
        float df0 = s_par[5], df1 = s_par[6];
        double eta0 = -M_PI*0.5 + 0.05, etaE = M_PI*0.5 - 0.05;
        double om0  = -M_PI + 0.05,     omE  = M_PI - 0.05;
        double deta = (S > 1) ? (etaE - eta0) / (double)(S - 1) : 0.0;
        double dom  = (S > 1) ? (omE  - om0)  / (double)(S - 1) : 0.0;
        for (int s = tid; s < S; s += 256) {
            float eta   = (float)(eta0 + s * deta);
            float omega = (float)(om0  + s * dom);
            float se = __builtin_amdgcn_sinf(eta   * INV_2PI);
            float ce = __builtin_amdgcn_cosf(eta   * INV_2PI);
            float so = __builtin_amdgcn_sinf(omega * INV_2PI);
            float co = __builtin_amdgcn_cosf(omega * INV_2PI);
            float fce = fexp_(ce, e1);
            float fse = fexp_(se, e1);
            float fco = fexp_(co, e2);
            float fso = fexp_(so, e2);
            float xx = sz0 * fce * fco;
            float yy = sz1 * fce * fso;
            float zz = sz2 * fse;
            float fx = df0 / sz2 * zz + 1.f;
            float fy = df1 / sz2 * zz + 1.f;
            float px = xx*fx, py = yy*fy, pz = zz;
            lds_pts[s] = make_float4(-2.f*px, -2.f*py, -2.f*pz,
                                     px*px + py*py + pz*pz);
        }
    }

    // ---- transform this thread's pcl point ----
    float R0=s_R[0],R1=s_R[1],R2=s_R[2],R3=s_R[3],R4=s_R[4],R5=s_R[5],
          R6=s_R[6],R7=s_R[7],R8=s_R[8],T0=s_R[9],T1=s_R[10],T2=s_R[11];

    int n0  = chunk * 256;
    int n   = n0 + tid;
    int cnt = min(256, N - n0);

    float qx=0.f, qy=0.f, qz=0.f, h=3.4e38f;
    if (n < N) {
        const float* p = pcl + ((size_t)b*N + n)*3;
        float px = p[0] - T0, py = p[1] - T1, pz = p[2] - T2;
        qx = R0*px + R1*py + R2*pz;
        qy = R3*px + R4*py + R5*pz;
        qz = R6*px + R7*py + R8*pz;
        h  = fmaf(qx,qx, fmaf(qy,qy, qz*qz));
    }
    lds_pcl[tid] = make_float4(qx, qy, qz, h);
    __syncthreads();

    // ---- pass A: min over s for this thread's n (LDS broadcast reads) ----
    if (n < N) {
        float ma=3.4e38f, mb=3.4e38f, mc=3.4e38f, md=3.4e38f;
        int s = 0;
        for (; s + 3 < S; s += 4) {
            float4 w0 = lds_pts[s+0], w1 = lds_pts[s+1],
                   w2 = lds_pts[s+2], w3 = lds_pts[s+3];
            float t0 = fmaf(w0.x,qx, fmaf(w0.y,qy, fmaf(w0.z,qz, w0.w)));
            float t1 = fmaf(w1.x,qx, fmaf(w1.y,qy, fmaf(w1.z,qz, w1.w)));
            float t2 = fmaf(w2.x,qx, fmaf(w2.y,qy, fmaf(w2.z,qz, w2.w)));
            float t3 = fmaf(w3.x,qx, fmaf(w3.y,qy, fmaf(w3.z,qz, w3.w)));
            ma = fminf(ma, t0); mb = fminf(mb, t1);
            mc = fminf(mc, t2); md = fminf(md, t3);
        }
        for (; s < S; ++s) {
            float4 w0 = lds_pts[s];
            ma = fminf(ma, fmaf(w0.x,qx, fmaf(w0.y,qy, fmaf(w0.z,qz, w0.w))));
        }
        d1[(size_t)bm*N + n] = fminf(fminf(ma, mb), fminf(mc, md)) + h;
    }

    // ---- pass B: min over this chunk's n for thread's s (no atomics) ----
    if (tid < S) {
        float4 w = lds_pts[tid];
        float ma=3.4e38f, mb=3.4e38f, mc=3.4e38f, md=3.4e38f;
        int j = 0;
        for (; j + 3 < cnt; j += 4) {
            float4 a = lds_pcl[j+0], bq = lds_pcl[j+1],
                   c = lds_pcl[j+2], dq = lds_pcl[j+3];
            float t0 = fmaf(w.x,a.x,  fmaf(w.y,a.y,  fmaf(w.z,a.z,  a.w)));
            float t1 = fmaf(w.x,bq.x, fmaf(w.y,bq.y, fmaf(w.z,bq.z, bq.w)));
            float t2 = fmaf(w.x,c.x,  fmaf(w.y,c.y,  fmaf(w.z,c.z,  c.w)));
            float t3 = fmaf(w.x,dq.x, fmaf(w.y,dq.y, fmaf(w.z,dq.z, dq.w)));
            ma = fminf(ma, t0); mb = fminf(mb, t1);
            mc = fminf(mc, t2); md = fminf(md, t3);
        }
        for (; j < cnt; ++j) {
            float4 a = lds_pcl[j];
            ma = fminf(ma, fmaf(w.x,a.x, fmaf(w.y,a.y, fmaf(w.z,a.z, a.w))));
        }
        float m2 = fminf(fminf(ma, mb), fminf(mc, md));
        d2part[((size_t)bm*nchunk + chunk)*256 + tid] = m2 + w.w;
    }
}

// ---------------- K1: cumsum + d2 reduce + (last block) final ----------------
__device__ __forceinline__ float block_reduce(float v, float* red) {
    int tid = threadIdx.x;
    red[tid] = v; __syncthreads();
    for (int off = 128; off > 0; off >>= 1) {
        if (tid < off) red[tid] += red[tid + off];
        __syncthreads();
    }
    float r = red[0];
    __syncthreads();
    return r;
}

__global__ void k_tail(const float* __restrict__ d1,     // [BM][N]
                       const float* __restrict__ prob,   // [B][M]
                       const float* __restrict__ emb,
                       const float* __restrict__ size,
                       const float* __restrict__ d2part, // [BM][nchunk][256]
                       float* __restrict__ d2min,        // [BM][256]
                       float* __restrict__ partial1,
                       unsigned* __restrict__ counter,
                       const int* __restrict__ Sptr,
                       float* __restrict__ out,
                       int B, int M, int N, int nb1, int nchunk)
{
    int tid = (int)threadIdx.x;
    int t = blockIdx.x * 256 + tid;
    int S = min(*Sptr, MAXS);
    int BM = B * M;
    __shared__ float red[256];

    // ---- phase 1a: pcl_to_prim partial (sort-free cumprod) ----
    float contrib = 0.f;
    if (t < B*N && M == MM) {
        int b = t / N, n = t - b*N;
        float d[MM], p[MM];
        #pragma unroll
        for (int m = 0; m < MM; ++m) {
            d[m] = d1[((size_t)(b*MM + m))*N + n];
            p[m] = prob[b*MM + m];
        }
        #pragma unroll
        for (int m = 0; m < MM; ++m) {
            float prod = p[m];
            #pragma unroll
            for (int mp = 0; mp < MM; ++mp) {
                if (mp == m) continue;
                bool before = (mp < m) ? (d[mp] <= d[m]) : (d[mp] < d[m]);
                prod *= before ? (1.f - p[mp]) : 1.f;
            }
            contrib += d[m] * prod;
        }
    }
    float psum = block_reduce(contrib, red);
    if (tid == 0) partial1[blockIdx.x] = psum;

    // ---- phase 1b: reduce d2part chunks -> d2min ----
    int total = BM * 256;
    for (int p = t; p < total; p += nb1 * 256) {
        int pbm = p >> 8, s = p & 255;
        if (s < S) {
            float mn = 3.4e38f;
            #pragma unroll 4
            for (int c = 0; c < nchunk; ++c)
                mn = fminf(mn, d2part[((size_t)pbm*nchunk + c)*256 + s]);
            d2min[p] = mn;
        }
    }

    // ---- last-block election ----
    __threadfence();
    __shared__ int s_last;
    if (tid == 0) s_last = (atomicAdd(counter, 1u) == (unsigned)(nb1 - 1)) ? 1 : 0;
    __syncthreads();
    if (!s_last) return;
    __threadfence();  // acquire

    // ---- final combine (single block) ----
    float v = 0.f;
    for (int i = tid; i < nb1; i += 256) v += partial1[i];
    float p2p = block_reduce(v, red) / (float)(B * N);

    __shared__ float s_area[256];
    if (tid < BM) {
        int b = tid / M, m = tid - (tid/M)*M;
        int best_i = 0; float best = emb[(size_t)(b*M + 0)*M + m];
        for (int i = 1; i < M; ++i) {
            float e = emb[(size_t)(b*M + i)*M + m];
            if (e > best) { best = e; best_i = i; }
        }
        const float* sg = size + (size_t)(b*M + best_i)*3;
        float a0=sg[0], a1=sg[1], a2=sg[2];
        float pa = fpow_(a0*a1, 1.6f), pb = fpow_(a0*a2, 1.6f), pc = fpow_(a1*a2, 1.6f);
        s_area[tid] = 4.f * 3.14159265358979323846f * fpow_((pa+pb+pc)*(1.f/3.f), 0.625f);
    }
    __syncthreads();

    float contrib2 = 0.f;
    int bm2 = tid >> 2, l = tid & 3;
    if (bm2 < BM) {
        float s2 = 0.f;
        for (int s = l; s < S; s += 4) {
            float dv = d2min[(size_t)bm2*256 + s];
            if (dv < 1e30f) s2 += dv;
        }
        s2 += __shfl_down(s2, 2, 4);
        s2 += __shfl_down(s2, 1, 4);
        if (l == 0) {
            int bb = bm2 / M;
            float sumb = 0.f;
            for (int mp = 0; mp < M; ++mp) sumb += s_area[bb*M + mp];
            float w = (float)M * s_area[bm2] / sumb;
            contrib2 = (s2 / (float)S) * w / (float)BM;
        }
    }
    float prim2pcl = block_reduce((l == 0 && bm2 < BM) ? contrib2 : 0.f, red);

    float a1 = 0.f, a2 = 0.f, a3 = 0.f;
    if (tid < BM) {
        int b = tid / M, m = tid - (tid/M)*M;
        float colsum = 0.f, rowsum = 0.f, ew = 0.f;
        for (int i = 0; i < M; ++i) colsum += emb[(size_t)(b*M + i)*M + m];
        for (int j = 0; j < M; ++j) {
            float e = emb[(size_t)(b*M + m)*M + j];
            rowsum += e;
            ew += e * (1.f - e);
        }
        a1 = (colsum - 1.f) * (colsum - 1.f);
        a2 = (rowsum - 1.f) * (rowsum - 1.f);
        a3 = ew;
    }
    float s1  = block_reduce(a1, red);
    float s2r = block_reduce(a2, red);
    float s3  = block_reduce(a3, red);
    float emb_reg = s1 / (float)BM + 10.f * s2r / (float)BM + s3 / (float)(BM * M);

    if (tid == 0) {
        out[1] = p2p;
        out[2] = prim2pcl;
        out[3] = 0.f;
        out[4] = emb_reg;
        out[0] = p2p + prim2pcl + emb_reg;
    }
}

// ---------------- host ----------------
extern "C" void kernel_launch(void* const* d_in, const int* in_sizes, int n_in,
                              void* d_out, int out_size, void* d_ws, size_t ws_size,
                              hipStream_t stream)
{
    const float* pcl    = (const float*)d_in[0];
    const float* trans  = (const float*)d_in[1];
    const float* rot    = (const float*)d_in[2];
    const float* size   = (const float*)d_in[3];
    const float* shapep = (const float*)d_in[4];
    const float* defo   = (const float*)d_in[5];
    const float* prob   = (const float*)d_in[6];
    const float* emb    = (const float*)d_in[7];
    const int*   Sptr   = (const int*)d_in[8];

    int M = in_sizes[7] / in_sizes[6];   // (B*M*M)/(B*M)
    int B = in_sizes[6] / M;
    int N = in_sizes[0] / (3 * B);
    int BM = B * M;
    int nchunk = (N + 255) / 256;
    int nb1    = (B * N + 255) / 256;

    float* ws = (float*)d_ws;
    size_t off = 0;
    float*    d1       = ws + off; off += (size_t)BM * N;
    float*    d2part   = ws + off; off += (size_t)BM * nchunk * 256;
    float*    d2min    = ws + off; off += (size_t)BM * 256;
    float*    partial1 = ws + off; off += (size_t)nb1;
    off = (off + 3) & ~(size_t)3;
    unsigned* counter  = (unsigned*)(ws + off);

    hipLaunchKernelGGL(k_main, dim3(BM * nchunk), dim3(256), 0, stream,
                       pcl, trans, rot, size, shapep, defo, emb, Sptr,
                       d1, d2part, counter, B, M, N, nchunk);
    hipLaunchKernelGGL(k_tail, dim3(nb1), dim3(256), 0, stream,
                       d1, prob, emb, size, d2part, d2min, partial1, counter,
                       Sptr, (float*)d_out, B, M, N, nb1, nchunk);
}

// Round 5
// 40.553 us; speedup vs baseline: 1.5176x; 1.0736x over previous
//
#include <hip/hip_runtime.h>
#include <math.h>

#define MAXS 256
#define MM 16   // M is 16 in this benchmark (derived from host sizes)

#define INV_2PI 0.15915494309189535f

typedef float f32x2 __attribute__((ext_vector_type(2)));

__device__ __forceinline__ f32x2 pk_fma_(f32x2 a, f32x2 b, f32x2 c) {
    f32x2 d;
    asm("v_pk_fma_f32 %0, %1, %2, %3" : "=v"(d) : "v"(a), "v"(b), "v"(c));
    return d;
}
__device__ __forceinline__ float min3_(float a, float b, float c) {
    float d;
    asm("v_min3_f32 %0, %1, %2, %3" : "=v"(d) : "v"(a), "v"(b), "v"(c));
    return d;
}

union F4 { float4 v; f32x2 p[2]; };

__device__ __forceinline__ float fpow_(float x, float p) {
    // x > 0 guaranteed. exp2/log2 hardware transcendentals.
    return __builtin_amdgcn_exp2f(p * __builtin_amdgcn_logf(x));
}
__device__ __forceinline__ float fexp_(float v, float p) {
    float s = (v > 0.f) ? 1.f : ((v < 0.f) ? -1.f : 0.f);
    return s * fpow_(fabsf(v) + 1e-6f, p);
}

// ---------------- K0: fused prep + distances (packed-pair math) ----------------
// LDS layout: point-pair AoS. ldsA[j] = (x0,x1,y0,y1), ldsB[j] = (z0,z1,w0,w1)
// where (x,y,z) = -2*pt and w = |pt|^2. Same for the pcl chunk with w = |q|^2.
// dist = |p|^2 - 2 p.q + |q|^2 -> 3 pk_fma + 1 min3 per 2 points.
__global__ void k_main(const float* __restrict__ pcl,
                       const float* __restrict__ trans,
                       const float* __restrict__ rot,
                       const float* __restrict__ size,
                       const float* __restrict__ shapep,
                       const float* __restrict__ defo,
                       const float* __restrict__ emb,
                       const int* __restrict__ Sptr,
                       float* __restrict__ d1,       // [BM][N]
                       float* __restrict__ d2part,   // [BM][nchunk][256]
                       unsigned* __restrict__ counter,
                       int B, int M, int N, int nchunk)
{
    int bm    = blockIdx.x / nchunk;
    int chunk = blockIdx.x - bm*nchunk;
    int b = bm / M, m = bm - b*M;
    int S = min(*Sptr, MAXS);
    int tid = (int)threadIdx.x;

    if (blockIdx.x == 0 && tid == 0) *counter = 0u;  // k_tail runs after us

    __shared__ float4 ldsA[MAXS/2], ldsB[MAXS/2];       // superquadric pts (pairs)
    __shared__ float4 pclA[128], pclB[128];             // pcl chunk (pairs)
    __shared__ float  s_R[12];
    __shared__ float  s_par[7]; // sz0,sz1,sz2,e1,e2,d0,d1

    // ---- prep: argmax_i emb[b,i,m] via 16-lane shuffle reduce (wave 0) ----
    if (tid < 64) {
        float v = (tid < 16 && tid < M) ? emb[(size_t)(b*M + tid)*M + m] : -3.4e38f;
        int idx = tid;
        #pragma unroll
        for (int off = 1; off < 16; off <<= 1) {
            float ov = __shfl_xor(v, off, 64);
            int   oi = __shfl_xor(idx, off, 64);
            if (ov > v || (ov == v && oi < idx)) { v = ov; idx = oi; }
        }
        if (tid == 0) {
            const float* sg = size   + (size_t)(b*M + idx)*3;
            const float* sh = shapep + (size_t)(b*M + idx)*2;
            const float* df = defo   + (size_t)(b*M + idx)*2;
            s_par[0]=sg[0]; s_par[1]=sg[1]; s_par[2]=sg[2];
            s_par[3]=sh[0]; s_par[4]=sh[1];
            s_par[5]=df[0]; s_par[6]=df[1];

            const float* q = rot + (size_t)(b*M + m)*4;
            float w=q[0], x=q[1], y=q[2], z=q[3];
            float inv = 1.0f / sqrtf(w*w + x*x + y*y + z*z);
            w*=inv; x*=inv; y*=inv; z*=inv;
            s_R[0] = 1.f - 2.f*(y*y + z*z); s_R[1] = 2.f*(x*y - w*z);       s_R[2] = 2.f*(x*z + w*y);
            s_R[3] = 2.f*(x*y + w*z);       s_R[4] = 1.f - 2.f*(x*x + z*z); s_R[5] = 2.f*(y*z - w*x);
            s_R[6] = 2.f*(x*z - w*y);       s_R[7] = 2.f*(y*z + w*x);       s_R[8] = 1.f - 2.f*(x*x + y*y);
            const float* tr = trans + (size_t)(b*M + m)*3;
            s_R[9] = tr[0]; s_R[10] = tr[1]; s_R[11] = tr[2];
        }
    }
    __syncthreads();

    // ---- prep: superquadric points -> LDS pairs ----
    {
        float sz0 = s_par[0], sz1 = s_par[1], sz2 = s_par[2];
        float e1  = s_par[3], e2  = s_par[4];
        float df0 = s_par[5], df1 = s_par[6];
        double eta0 = -M_PI*0.5 + 0.05, etaE = M_PI*0.5 - 0.05;
        double om0  = -M_PI + 0.05,     omE  = M_PI - 0.05;
        double deta = (S > 1) ? (etaE - eta0) / (double)(S - 1) : 0.0;
        double dom  = (S > 1) ? (omE  - om0)  / (double)(S - 1) : 0.0;
        int Spad = (S + 3) & ~3;
        for (int s = tid; s < Spad; s += 256) {
            float px=0.f, py=0.f, pz=0.f, ps2=3.4e38f;
            if (s < S) {
                float eta   = (float)(eta0 + s * deta);
                float omega = (float)(om0  + s * dom);
                float se = __builtin_amdgcn_sinf(eta   * INV_2PI);
                float ce = __builtin_amdgcn_cosf(eta   * INV_2PI);
                float so = __builtin_amdgcn_sinf(omega * INV_2PI);
                float co = __builtin_amdgcn_cosf(omega * INV_2PI);
                float fce = fexp_(ce, e1);
                float fse = fexp_(se, e1);
                float fco = fexp_(co, e2);
                float fso = fexp_(so, e2);
                float xx = sz0 * fce * fco;
                float yy = sz1 * fce * fso;
                float zz = sz2 * fse;
                float fx = df0 / sz2 * zz + 1.f;
                float fy = df1 / sz2 * zz + 1.f;
                px = xx*fx; py = yy*fy; pz = zz;
                ps2 = px*px + py*py + pz*pz;
            }
            int pr = s >> 1, hf = s & 1;
            ((float*)&ldsA[pr])[hf]     = -2.f*px;
            ((float*)&ldsA[pr])[2 + hf] = -2.f*py;
            ((float*)&ldsB[pr])[hf]     = -2.f*pz;
            ((float*)&ldsB[pr])[2 + hf] = ps2;
        }
    }

    // ---- transform this thread's pcl point, stage into pair layout ----
    float R0=s_R[0],R1=s_R[1],R2=s_R[2],R3=s_R[3],R4=s_R[4],R5=s_R[5],
          R6=s_R[6],R7=s_R[7],R8=s_R[8],T0=s_R[9],T1=s_R[10],T2=s_R[11];

    int n0  = chunk * 256;
    int n   = n0 + tid;

    float qx=0.f, qy=0.f, qz=0.f, h=3.4e38f;
    if (n < N) {
        const float* p = pcl + ((size_t)b*N + n)*3;
        float px = p[0] - T0, py = p[1] - T1, pz = p[2] - T2;
        qx = R0*px + R1*py + R2*pz;
        qy = R3*px + R4*py + R5*pz;
        qz = R6*px + R7*py + R8*pz;
        h  = fmaf(qx,qx, fmaf(qy,qy, qz*qz));
    }
    {
        int pr = tid >> 1, hf = tid & 1;
        ((float*)&pclA[pr])[hf]     = qx;
        ((float*)&pclA[pr])[2 + hf] = qy;
        ((float*)&pclB[pr])[hf]     = qz;
        ((float*)&pclB[pr])[2 + hf] = h;
    }
    __syncthreads();

    // ---- pass A: min over s for this thread's n ----
    if (n < N) {
        f32x2 qx2 = {qx,qx}, qy2 = {qy,qy}, qz2 = {qz,qz};
        float ma = 3.4e38f, mb = 3.4e38f;
        int npair = (S + 1) >> 1;
        int np2 = npair & ~1;
        int j = 0;
        for (; j < np2; j += 2) {
            F4 A0, B0, A1, B1;
            A0.v = ldsA[j];   B0.v = ldsB[j];
            A1.v = ldsA[j+1]; B1.v = ldsB[j+1];
            f32x2 t0 = pk_fma_(A0.p[0], qx2, pk_fma_(A0.p[1], qy2, pk_fma_(B0.p[0], qz2, B0.p[1])));
            f32x2 t1 = pk_fma_(A1.p[0], qx2, pk_fma_(A1.p[1], qy2, pk_fma_(B1.p[0], qz2, B1.p[1])));
            ma = min3_(ma, t0.x, t0.y);
            mb = min3_(mb, t1.x, t1.y);
        }
        for (; j < npair; ++j) {
            F4 A0, B0; A0.v = ldsA[j]; B0.v = ldsB[j];
            f32x2 t0 = pk_fma_(A0.p[0], qx2, pk_fma_(A0.p[1], qy2, pk_fma_(B0.p[0], qz2, B0.p[1])));
            ma = min3_(ma, t0.x, t0.y);
        }
        d1[(size_t)bm*N + n] = fminf(ma, mb) + h;
    }

    // ---- pass B: min over this chunk's n for thread's s ----
    if (tid < S) {
        int pr = tid >> 1, hf = tid & 1;
        float m2x = ((const float*)&ldsA[pr])[hf];
        float m2y = ((const float*)&ldsA[pr])[2 + hf];
        float m2z = ((const float*)&ldsB[pr])[hf];
        float pw2 = ((const float*)&ldsB[pr])[2 + hf];
        f32x2 px2 = {m2x,m2x}, py2 = {m2y,m2y}, pz2 = {m2z,m2z};
        float ma = 3.4e38f, mb = 3.4e38f;
        #pragma unroll 2
        for (int j = 0; j < 128; j += 2) {
            F4 A0, B0, A1, B1;
            A0.v = pclA[j];   B0.v = pclB[j];
            A1.v = pclA[j+1]; B1.v = pclB[j+1];
            f32x2 t0 = pk_fma_(A0.p[0], px2, pk_fma_(A0.p[1], py2, pk_fma_(B0.p[0], pz2, B0.p[1])));
            f32x2 t1 = pk_fma_(A1.p[0], px2, pk_fma_(A1.p[1], py2, pk_fma_(B1.p[0], pz2, B1.p[1])));
            ma = min3_(ma, t0.x, t0.y);
            mb = min3_(mb, t1.x, t1.y);
        }
        d2part[((size_t)bm*nchunk + chunk)*256 + tid] = fminf(ma, mb) + pw2;
    }
}

// ---------------- K1: cumsum + d2 reduce + (last block) final ----------------
__device__ __forceinline__ float block_reduce(float v, float* red) {
    int tid = threadIdx.x;
    red[tid] = v; __syncthreads();
    for (int off = 128; off > 0; off >>= 1) {
        if (tid < off) red[tid] += red[tid + off];
        __syncthreads();
    }
    float r = red[0];
    __syncthreads();
    return r;
}

__global__ void k_tail(const float* __restrict__ d1,     // [BM][N]
                       const float* __restrict__ prob,   // [B][M]
                       const float* __restrict__ emb,
                       const float* __restrict__ size,
                       const float* __restrict__ d2part, // [BM][nchunk][256]
                       float* __restrict__ d2min,        // [BM][256]
                       float* __restrict__ partial1,
                       unsigned* __restrict__ counter,
                       const int* __restrict__ Sptr,
                       float* __restrict__ out,
                       int B, int M, int N, int nb1, int nchunk)
{
    int tid = (int)threadIdx.x;
    int t = blockIdx.x * 256 + tid;
    int S = min(*Sptr, MAXS);
    int BM = B * M;
    __shared__ float red[256];

    // ---- phase 1a: pcl_to_prim partial (sort-free cumprod) ----
    float contrib = 0.f;
    if (t < B*N && M == MM) {
        int b = t / N, n = t - b*N;
        float d[MM], p[MM];
        #pragma unroll
        for (int m = 0; m < MM; ++m) {
            d[m] = d1[((size_t)(b*MM + m))*N + n];
            p[m] = prob[b*MM + m];
        }
        #pragma unroll
        for (int m = 0; m < MM; ++m) {
            float prod = p[m];
            #pragma unroll
            for (int mp = 0; mp < MM; ++mp) {
                if (mp == m) continue;
                bool before = (mp < m) ? (d[mp] <= d[m]) : (d[mp] < d[m]);
                prod *= before ? (1.f - p[mp]) : 1.f;
            }
            contrib += d[m] * prod;
        }
    }
    float psum = block_reduce(contrib, red);
    if (tid == 0) partial1[blockIdx.x] = psum;

    // ---- phase 1b: reduce d2part chunks -> d2min ----
    int total = BM * 256;
    for (int p = t; p < total; p += nb1 * 256) {
        int pbm = p >> 8, s = p & 255;
        if (s < S) {
            float mn = 3.4e38f;
            #pragma unroll 4
            for (int c = 0; c < nchunk; ++c)
                mn = fminf(mn, d2part[((size_t)pbm*nchunk + c)*256 + s]);
            d2min[p] = mn;
        }
    }

    // ---- last-block election ----
    __threadfence();
    __shared__ int s_last;
    if (tid == 0) s_last = (atomicAdd(counter, 1u) == (unsigned)(nb1 - 1)) ? 1 : 0;
    __syncthreads();
    if (!s_last) return;
    __threadfence();  // acquire

    // ---- final combine (single block) ----
    float v = 0.f;
    for (int i = tid; i < nb1; i += 256) v += partial1[i];
    float p2p = block_reduce(v, red) / (float)(B * N);

    __shared__ float s_area[256];
    if (tid < BM) {
        int b = tid / M, m = tid - (tid/M)*M;
        int best_i = 0; float best = emb[(size_t)(b*M + 0)*M + m];
        for (int i = 1; i < M; ++i) {
            float e = emb[(size_t)(b*M + i)*M + m];
            if (e > best) { best = e; best_i = i; }
        }
        const float* sg = size + (size_t)(b*M + best_i)*3;
        float a0=sg[0], a1=sg[1], a2=sg[2];
        float pa = fpow_(a0*a1, 1.6f), pb = fpow_(a0*a2, 1.6f), pc = fpow_(a1*a2, 1.6f);
        s_area[tid] = 4.f * 3.14159265358979323846f * fpow_((pa+pb+pc)*(1.f/3.f), 0.625f);
    }
    __syncthreads();

    float contrib2 = 0.f;
    int bm2 = tid >> 2, l = tid & 3;
    if (bm2 < BM) {
        float s2 = 0.f;
        for (int s = l; s < S; s += 4) {
            float dv = d2min[(size_t)bm2*256 + s];
            if (dv < 1e30f) s2 += dv;
        }
        s2 += __shfl_down(s2, 2, 4);
        s2 += __shfl_down(s2, 1, 4);
        if (l == 0) {
            int bb = bm2 / M;
            float sumb = 0.f;
            for (int mp = 0; mp < M; ++mp) sumb += s_area[bb*M + mp];
            float w = (float)M * s_area[bm2] / sumb;
            contrib2 = (s2 / (float)S) * w / (float)BM;
        }
    }
    float prim2pcl = block_reduce((l == 0 && bm2 < BM) ? contrib2 : 0.f, red);

    float a1 = 0.f, a2 = 0.f, a3 = 0.f;
    if (tid < BM) {
        int b = tid / M, m = tid - (tid/M)*M;
        float colsum = 0.f, rowsum = 0.f, ew = 0.f;
        for (int i = 0; i < M; ++i) colsum += emb[(size_t)(b*M + i)*M + m];
        for (int j = 0; j < M; ++j) {
            float e = emb[(size_t)(b*M + m)*M + j];
            rowsum += e;
            ew += e * (1.f - e);
        }
        a1 = (colsum - 1.f) * (colsum - 1.f);
        a2 = (rowsum - 1.f) * (rowsum - 1.f);
        a3 = ew;
    }
    float s1  = block_reduce(a1, red);
    float s2r = block_reduce(a2, red);
    float s3  = block_reduce(a3, red);
    float emb_reg = s1 / (float)BM + 10.f * s2r / (float)BM + s3 / (float)(BM * M);

    if (tid == 0) {
        out[1] = p2p;
        out[2] = prim2pcl;
        out[3] = 0.f;
        out[4] = emb_reg;
        out[0] = p2p + prim2pcl + emb_reg;
    }
}

// ---------------- host ----------------
extern "C" void kernel_launch(void* const* d_in, const int* in_sizes, int n_in,
                              void* d_out, int out_size, void* d_ws, size_t ws_size,
                              hipStream_t stream)
{
    const float* pcl    = (const float*)d_in[0];
    const float* trans  = (const float*)d_in[1];
    const float* rot    = (const float*)d_in[2];
    const float* size   = (const float*)d_in[3];
    const float* shapep = (const float*)d_in[4];
    const float* defo   = (const float*)d_in[5];
    const float* prob   = (const float*)d_in[6];
    const float* emb    = (const float*)d_in[7];
    const int*   Sptr   = (const int*)d_in[8];

    int M = in_sizes[7] / in_sizes[6];   // (B*M*M)/(B*M)
    int B = in_sizes[6] / M;
    int N = in_sizes[0] / (3 * B);
    int BM = B * M;
    int nchunk = (N + 255) / 256;
    int nb1    = (B * N + 255) / 256;

    float* ws = (float*)d_ws;
    size_t off = 0;
    float*    d1       = ws + off; off += (size_t)BM * N;
    float*    d2part   = ws + off; off += (size_t)BM * nchunk * 256;
    float*    d2min    = ws + off; off += (size_t)BM * 256;
    float*    partial1 = ws + off; off += (size_t)nb1;
    off = (off + 3) & ~(size_t)3;
    unsigned* counter  = (unsigned*)(ws + off);

    hipLaunchKernelGGL(k_main, dim3(BM * nchunk), dim3(256), 0, stream,
                       pcl, trans, rot, size, shapep, defo, emb, Sptr,
                       d1, d2part, counter, B, M, N, nchunk);
    hipLaunchKernelGGL(k_tail, dim3(nb1), dim3(256), 0, stream,
                       d1, prob, emb, size, d2part, d2min, partial1, counter,
                       Sptr, (float*)d_out, B, M, N, nb1, nchunk);
}